// Round 9
// baseline (296.172 us; speedup 1.0000x reference)
//
#include <hip/hip_runtime.h>
#include <math.h>

#define EPS 1e-8f
#define KT 32
#define KC1 2
#define SCAT 512     // scatter blocks inside fused K1
#define NG1 512      // gemm1 blocks inside fused K1 (= (S/32)*KC1)
#define NS2 64       // gemm2 split-K chunks

// ---------------------------------------------------------------------------
// K0: norms + W-zero + cnt-zero.
//  Blocks [0,S): rinv[s] = 1/(||S_s||+eps)  AND zero W row s (D floats).
//  Blocks [S, S+B): Hs[b,:] = H[b,:]/(||H_b||+eps), gscale[b]=0.005*||G_b||
// ---------------------------------------------------------------------------
__global__ void k_norms(const float* __restrict__ Sg, const float* __restrict__ Hg,
                        const float* __restrict__ Gg, float* __restrict__ rinv,
                        float* __restrict__ Hs, float* __restrict__ gscale,
                        float* __restrict__ W, int* __restrict__ cnt,
                        int Srows, int Fdim, int Bdim, int Dd) {
    __shared__ float wsum[4];
    __shared__ float wsum2[4];
    __shared__ float bc0;
    int row = blockIdx.x;
    int tid = threadIdx.x;
    int lane = tid & 63, wv = tid >> 6;

    if (row < Srows) {
        if (row == 0 && tid < 16) cnt[tid] = 0;   // epilogue counters
        // zero W row (Dd floats, float4 stores)
        float4 z4 = {0.f, 0.f, 0.f, 0.f};
        float4* wp = (float4*)(W + (size_t)row * Dd);
        for (int i = tid; i < Dd / 4; i += 256) wp[i] = z4;

        const float* p = Sg + (size_t)row * Fdim;
        float acc = 0.f;
        for (int i = tid; i < Fdim; i += 256) { float v = p[i]; acc += v * v; }
        for (int off = 32; off > 0; off >>= 1) acc += __shfl_down(acc, off, 64);
        if (lane == 0) wsum[wv] = acc;
        __syncthreads();
        if (tid == 0) {
            float t = wsum[0] + wsum[1] + wsum[2] + wsum[3];
            rinv[row] = 1.0f / (sqrtf(t) + EPS);
        }
    } else {
        int b = row - Srows;
        if (b >= Bdim) return;
        const float* ph = Hg + (size_t)b * Fdim;
        const float* pg = Gg + (size_t)b * Fdim;
        float ah = 0.f, ag = 0.f;
        for (int i = tid; i < Fdim; i += 256) {
            float h = ph[i]; ah += h * h;
            float g = pg[i]; ag += g * g;
        }
        for (int off = 32; off > 0; off >>= 1) {
            ah += __shfl_down(ah, off, 64);
            ag += __shfl_down(ag, off, 64);
        }
        if (lane == 0) { wsum[wv] = ah; wsum2[wv] = ag; }
        __syncthreads();
        if (tid == 0) {
            float th = wsum[0] + wsum[1] + wsum[2] + wsum[3];
            float tg = wsum2[0] + wsum2[1] + wsum2[2] + wsum2[3];
            bc0 = 1.0f / (sqrtf(th) + EPS);
            gscale[b] = 0.005f * sqrtf(tg);
        }
        __syncthreads();
        float hn = bc0;
        float* dst = Hs + (size_t)b * Fdim;
        for (int i = tid; i < Fdim; i += 256) dst[i] = ph[i] * hn;
    }
}

// ---------------------------------------------------------------------------
// K1 fused: blocks [0,NG1) = GEMM1, blocks [NG1, NG1+SCAT) = edge scatter.
// (R7-proven: VALU-bound gemm co-resident with latency/atomic-bound scatter.)
// ---------------------------------------------------------------------------
__global__ __launch_bounds__(256) void k_g1scat(
        const float* __restrict__ Hs, const float* __restrict__ Sg,
        const float* __restrict__ rinv, float* __restrict__ Pt_part,
        const float* __restrict__ ew, const int* __restrict__ ed,
        const int* __restrict__ es, float* __restrict__ W,
        float* __restrict__ pcs,
        int Srows, int Fdim, int kchunk, int E, int Dd) {
    __shared__ float smem[KT * 104];
    #define LA(k, i) smem[(k) * 68 + (i)]
    #define LB(k, i) smem[KT * 68 + (k) * 36 + (i)]
    int id = blockIdx.x;
    int tid = threadIdx.x;

    if (id < NG1) {
        int tx = tid & 15;          // b: 4 each
        int ty = tid >> 4;          // s: 2 each
        int s0 = (id & 255) * 32;
        int kb = (id >> 8) * kchunk;

        float4 acc0 = {0.f, 0.f, 0.f, 0.f};
        float4 acc1 = {0.f, 0.f, 0.f, 0.f};

        for (int kt = 0; kt < kchunk; kt += KT) {
            #pragma unroll
            for (int i = 0; i < 8; i++) {
                int idx = tid + i * 256;
                int c = idx & 31, r = idx >> 5;
                LA(c, r) = Hs[(size_t)r * Fdim + kb + kt + c];
            }
            #pragma unroll
            for (int i = 0; i < 4; i++) {
                int idx = tid + i * 256;
                int c = idx & 31, r = idx >> 5;
                LB(c, r) = Sg[(size_t)(s0 + r) * Fdim + kb + kt + c];
            }
            __syncthreads();
            #pragma unroll
            for (int k = 0; k < KT; k++) {
                float4 hv = *(const float4*)&LA(k, tx * 4);
                float2 sv = *(const float2*)&LB(k, ty * 2);
                acc0.x += sv.x * hv.x; acc0.y += sv.x * hv.y;
                acc0.z += sv.x * hv.z; acc0.w += sv.x * hv.w;
                acc1.x += sv.y * hv.x; acc1.y += sv.y * hv.y;
                acc1.z += sv.y * hv.z; acc1.w += sv.y * hv.w;
            }
            __syncthreads();
        }
        int sa = s0 + ty * 2;
        float r0 = rinv[sa], r1 = rinv[sa + 1];
        float4 o0, o1;
        o0.x = acc0.x * r0; o0.y = acc0.y * r0; o0.z = acc0.z * r0; o0.w = acc0.w * r0;
        o1.x = acc1.x * r1; o1.y = acc1.y * r1; o1.z = acc1.z * r1; o1.w = acc1.w * r1;
        size_t base = (size_t)(id >> 8) * Srows;
        *(float4*)&Pt_part[(base + sa) * 64 + tx * 4]     = o0;
        *(float4*)&Pt_part[(base + sa + 1) * 64 + tx * 4] = o1;
    } else {
        int sid = id - NG1;
        float* bins = smem;
        for (int i = tid; i < Dd; i += 256) bins[i] = 0.f;
        __syncthreads();
        int stride = SCAT * 256;
        for (int e = sid * 256 + tid; e < E; e += stride) {
            int s = es[e];
            int d = ed[e];
            float w = ew[e];
            atomicAdd(&W[(size_t)s * Dd + d], w);
            atomicAdd(&bins[d], w);
        }
        __syncthreads();
        float* dst = pcs + (size_t)sid * Dd;
        for (int i = tid; i < Dd; i += 256) dst[i] = bins[i];
    }
    #undef LA
    #undef LB
}

// ---------------------------------------------------------------------------
// K2: GEMM2 + fused epilogue (split-K last-arriver fixup).
// part[kc][b][d] = sum_{k in chunk kc} P'[b,k] * W[k,d]; the 64th block to
// finish a d-tile reduces pcs->colsum, sums parts, applies gscale, writes out.
// Grid (D/64, NS2) = 1024 blocks = 4 waves/SIMD.
// ---------------------------------------------------------------------------
__global__ __launch_bounds__(256) void k_gemm2(
        const float* __restrict__ Pt_part, const float* __restrict__ W,
        float* __restrict__ part, const float* __restrict__ pcs,
        const float* __restrict__ gscale, float* __restrict__ out,
        int* __restrict__ cnt, int Srows, int Dd) {
    __shared__ float lA[KT][64];    // [k][b]
    __shared__ float lB[KT][64];    // [k][d]
    __shared__ int bc_old;
    int tid = threadIdx.x;
    int tx = tid & 15;   // d: 4 each
    int ty = tid >> 4;   // b: 4 each
    int dt = blockIdx.x;
    int d0 = dt * 64;
    int kchunk = Srows / NS2;          // 128
    int kb = blockIdx.y * kchunk;
    size_t half = (size_t)Srows * 64;

    float4 acc[4];
    #pragma unroll
    for (int j = 0; j < 4; j++) { acc[j].x = acc[j].y = acc[j].z = acc[j].w = 0.f; }

    for (int kt = 0; kt < kchunk; kt += KT) {
        #pragma unroll
        for (int i = 0; i < 8; i++) {          // 32k x 64b
            int idx = tid + i * 256;
            int r = idx & 63, c = idx >> 6;    // r=b, c=k
            size_t src = (size_t)(kb + kt + c) * 64 + r;
            lA[c][r] = Pt_part[src] + Pt_part[half + src];
        }
        #pragma unroll
        for (int i = 0; i < 8; i++) {          // 32k x 64d
            int idx = tid + i * 256;
            int c = idx & 63, r = idx >> 6;    // c=d, r=k
            lB[r][c] = W[(size_t)(kb + kt + r) * Dd + d0 + c];
        }
        __syncthreads();
        #pragma unroll
        for (int k = 0; k < KT; k++) {
            float4 av = *(const float4*)&lA[k][ty * 4];
            float4 bv = *(const float4*)&lB[k][tx * 4];
            acc[0].x += av.x * bv.x; acc[0].y += av.x * bv.y; acc[0].z += av.x * bv.z; acc[0].w += av.x * bv.w;
            acc[1].x += av.y * bv.x; acc[1].y += av.y * bv.y; acc[1].z += av.y * bv.z; acc[1].w += av.y * bv.w;
            acc[2].x += av.z * bv.x; acc[2].y += av.z * bv.y; acc[2].z += av.z * bv.z; acc[2].w += av.z * bv.w;
            acc[3].x += av.w * bv.x; acc[3].y += av.w * bv.y; acc[3].z += av.w * bv.z; acc[3].w += av.w * bv.w;
        }
        __syncthreads();
    }
    #pragma unroll
    for (int j = 0; j < 4; j++) {
        int b = ty * 4 + j;
        *(float4*)&part[((size_t)blockIdx.y * 64 + b) * Dd + d0 + tx * 4] = acc[j];
    }

    // --- last-arriver fixup for this d-tile ---
    __threadfence();                       // release: part writes visible
    __syncthreads();
    if (tid == 0) bc_old = atomicAdd(&cnt[dt], 1);
    __syncthreads();
    if (bc_old != NS2 - 1) return;
    __threadfence();                       // acquire: see all parts + pcs

    // colsum for d0..d0+63: thread (q=tid>>6) sums 128 of 512 pcs rows
    {
        int dl = tid & 63, q = tid >> 6;
        float s = 0.f;
        const float* pp = pcs + d0 + dl;
        #pragma unroll 8
        for (int c = q * 128; c < (q + 1) * 128; c++)
            s += pp[(size_t)c * Dd];
        lA[0][0 + q * 64 + dl > 0 ? 0 : 0]; // no-op guard (keep layout simple)
        ((float*)lB)[q * 64 + dl] = s;
    }
    __syncthreads();
    if (tid < 64)
        ((float*)lA)[tid] = ((float*)lB)[tid] + ((float*)lB)[64 + tid]
                          + ((float*)lB)[128 + tid] + ((float*)lB)[192 + tid];
    __syncthreads();
    // out[b][d0+dl] = gscale[b] * (sum_kc part[kc][b][d0+dl] + colsum)
    {
        int dl = tid & 63;
        int br = tid >> 6;
        for (int j = 0; j < 16; j++) {
            int b = j * 4 + br;
            float s = 0.f;
            const float* sp = part + (size_t)b * Dd + d0 + dl;
            #pragma unroll 8
            for (int kcc = 0; kcc < NS2; kcc++)
                s += sp[(size_t)kcc * 64 * Dd];
            out[(size_t)b * Dd + d0 + dl] = gscale[b] * (s + ((float*)lA)[dl]);
        }
    }
}

extern "C" void kernel_launch(void* const* d_in, const int* in_sizes, int n_in,
                              void* d_out, int out_size, void* d_ws, size_t ws_size,
                              hipStream_t stream) {
    const float* H  = (const float*)d_in[0];
    const float* G  = (const float*)d_in[1];
    const float* Sg = (const float*)d_in[2];
    const float* ew = (const float*)d_in[3];
    const int*   ed = (const int*)d_in[4];
    const int*   es = (const int*)d_in[5];

    const int B = 64;
    const int F = in_sizes[0] / B;        // 512
    const int S = in_sizes[2] / F;        // 8192
    const int E = in_sizes[3];            // 500000
    const int D = out_size / B;           // 1024
    float* out = (float*)d_out;

    // workspace layout (floats); every buffer fully written before read
    float* ws = (float*)d_ws;
    size_t off = 0;
    float* rinv    = ws + off; off += (size_t)S;                 // 8192
    float* Hs      = ws + off; off += (size_t)B * F;             // 32768
    float* gscale  = ws + off; off += 256;
    int*   cnt     = (int*)(ws + off); off += 256;
    float* W       = ws + off; off += (size_t)S * D;             // 8.39M
    float* Pt_part = ws + off; off += (size_t)KC1 * S * B;       // 1.05M
    float* pcs     = ws + off; off += (size_t)SCAT * D;          // 524288
    float* part    = ws + off; off += (size_t)NS2 * B * D;       // 4.19M

    // K0: norms + W-zero + cnt-zero
    k_norms<<<S + B, 256, 0, stream>>>(Sg, H, G, rinv, Hs, gscale, W, cnt,
                                       S, F, B, D);
    // K1: gemm1 (512 blocks) || scatter (512 blocks)
    k_g1scat<<<NG1 + SCAT, 256, 0, stream>>>(Hs, Sg, rinv, Pt_part,
                                             ew, ed, es, W, pcs,
                                             S, F, F / KC1, E, D);
    // K2: gemm2 + fused colsum/epilogue (last-arriver per d-tile)
    dim3 g2(D / 64, NS2);
    k_gemm2<<<g2, 256, 0, stream>>>(Pt_part, W, part, pcs, gscale, out,
                                    cnt, S, D);
}

// Round 10
// 155.280 us; speedup vs baseline: 1.9073x; 1.9073x over previous
//
#include <hip/hip_runtime.h>
#include <math.h>

#define EPS 1e-8f
#define KT 32
#define KC1 2
#define SCAT 512     // scatter blocks inside fused K1
#define NG1 512      // gemm1 blocks inside fused K1 (= (S/32)*KC1)
#define NS2 64       // gemm2 split-K chunks

// ---------------------------------------------------------------------------
// K0: norms + W-zero.
//  Blocks [0,S): rinv[s] = 1/(||S_s||+eps)  AND zero W row s (D floats).
//  Blocks [S, S+B): Hs[b,:] = H[b,:]/(||H_b||+eps), gscale[b]=0.005*||G_b||
// ---------------------------------------------------------------------------
__global__ void k_norms(const float* __restrict__ Sg, const float* __restrict__ Hg,
                        const float* __restrict__ Gg, float* __restrict__ rinv,
                        float* __restrict__ Hs, float* __restrict__ gscale,
                        float* __restrict__ W,
                        int Srows, int Fdim, int Bdim, int Dd) {
    __shared__ float wsum[4];
    __shared__ float wsum2[4];
    __shared__ float bc0;
    int row = blockIdx.x;
    int tid = threadIdx.x;
    int lane = tid & 63, wv = tid >> 6;

    if (row < Srows) {
        // zero W row (Dd floats, float4 stores)
        float4 z4 = {0.f, 0.f, 0.f, 0.f};
        float4* wp = (float4*)(W + (size_t)row * Dd);
        for (int i = tid; i < Dd / 4; i += 256) wp[i] = z4;

        const float* p = Sg + (size_t)row * Fdim;
        float acc = 0.f;
        for (int i = tid; i < Fdim; i += 256) { float v = p[i]; acc += v * v; }
        for (int off = 32; off > 0; off >>= 1) acc += __shfl_down(acc, off, 64);
        if (lane == 0) wsum[wv] = acc;
        __syncthreads();
        if (tid == 0) {
            float t = wsum[0] + wsum[1] + wsum[2] + wsum[3];
            rinv[row] = 1.0f / (sqrtf(t) + EPS);
        }
    } else {
        int b = row - Srows;
        if (b >= Bdim) return;
        const float* ph = Hg + (size_t)b * Fdim;
        const float* pg = Gg + (size_t)b * Fdim;
        float ah = 0.f, ag = 0.f;
        for (int i = tid; i < Fdim; i += 256) {
            float h = ph[i]; ah += h * h;
            float g = pg[i]; ag += g * g;
        }
        for (int off = 32; off > 0; off >>= 1) {
            ah += __shfl_down(ah, off, 64);
            ag += __shfl_down(ag, off, 64);
        }
        if (lane == 0) { wsum[wv] = ah; wsum2[wv] = ag; }
        __syncthreads();
        if (tid == 0) {
            float th = wsum[0] + wsum[1] + wsum[2] + wsum[3];
            float tg = wsum2[0] + wsum2[1] + wsum2[2] + wsum2[3];
            bc0 = 1.0f / (sqrtf(th) + EPS);
            gscale[b] = 0.005f * sqrtf(tg);
        }
        __syncthreads();
        float hn = bc0;
        float* dst = Hs + (size_t)b * Fdim;
        for (int i = tid; i < Fdim; i += 256) dst[i] = ph[i] * hn;
    }
}

// ---------------------------------------------------------------------------
// K1 fused: blocks [0,NG1) = GEMM1, blocks [NG1, NG1+SCAT) = edge scatter.
// Independent work co-resident per CU: VALU-bound gemm overlaps
// latency/atomic-bound scatter.  (R7-proven structure; do not add
// cross-block fences here — R9 showed device-scope fences cost ~100+ us.)
// ---------------------------------------------------------------------------
__global__ __launch_bounds__(256) void k_g1scat(
        const float* __restrict__ Hs, const float* __restrict__ Sg,
        const float* __restrict__ rinv, float* __restrict__ Pt_part,
        const float* __restrict__ ew, const int* __restrict__ ed,
        const int* __restrict__ es, float* __restrict__ W,
        float* __restrict__ pcs,
        int Srows, int Fdim, int kchunk, int E, int Dd) {
    // union LDS: gemm1 needs 32*(68+36)=3328 floats; scatter needs Dd (1024)
    __shared__ float smem[KT * 104];
    #define LA(k, i) smem[(k) * 68 + (i)]
    #define LB(k, i) smem[KT * 68 + (k) * 36 + (i)]
    int id = blockIdx.x;
    int tid = threadIdx.x;

    if (id < NG1) {
        int tx = tid & 15;          // b: 4 each
        int ty = tid >> 4;          // s: 2 each
        int s0 = (id & 255) * 32;
        int kb = (id >> 8) * kchunk;

        float4 acc0 = {0.f, 0.f, 0.f, 0.f};
        float4 acc1 = {0.f, 0.f, 0.f, 0.f};

        for (int kt = 0; kt < kchunk; kt += KT) {
            #pragma unroll
            for (int i = 0; i < 8; i++) {
                int idx = tid + i * 256;
                int c = idx & 31, r = idx >> 5;
                LA(c, r) = Hs[(size_t)r * Fdim + kb + kt + c];
            }
            #pragma unroll
            for (int i = 0; i < 4; i++) {
                int idx = tid + i * 256;
                int c = idx & 31, r = idx >> 5;
                LB(c, r) = Sg[(size_t)(s0 + r) * Fdim + kb + kt + c];
            }
            __syncthreads();
            #pragma unroll
            for (int k = 0; k < KT; k++) {
                float4 hv = *(const float4*)&LA(k, tx * 4);
                float2 sv = *(const float2*)&LB(k, ty * 2);
                acc0.x += sv.x * hv.x; acc0.y += sv.x * hv.y;
                acc0.z += sv.x * hv.z; acc0.w += sv.x * hv.w;
                acc1.x += sv.y * hv.x; acc1.y += sv.y * hv.y;
                acc1.z += sv.y * hv.z; acc1.w += sv.y * hv.w;
            }
            __syncthreads();
        }
        int sa = s0 + ty * 2;
        float r0 = rinv[sa], r1 = rinv[sa + 1];
        float4 o0, o1;
        o0.x = acc0.x * r0; o0.y = acc0.y * r0; o0.z = acc0.z * r0; o0.w = acc0.w * r0;
        o1.x = acc1.x * r1; o1.y = acc1.y * r1; o1.z = acc1.z * r1; o1.w = acc1.w * r1;
        size_t base = (size_t)(id >> 8) * Srows;
        *(float4*)&Pt_part[(base + sa) * 64 + tx * 4]     = o0;
        *(float4*)&Pt_part[(base + sa + 1) * 64 + tx * 4] = o1;
    } else {
        int sid = id - NG1;
        float* bins = smem;                    // reuse LDS
        for (int i = tid; i < Dd; i += 256) bins[i] = 0.f;
        __syncthreads();
        int stride = SCAT * 256;
        for (int e = sid * 256 + tid; e < E; e += stride) {
            int s = es[e];
            int d = ed[e];
            float w = ew[e];
            atomicAdd(&W[(size_t)s * Dd + d], w);
            atomicAdd(&bins[d], w);
        }
        __syncthreads();
        float* dst = pcs + (size_t)sid * Dd;
        for (int i = tid; i < Dd; i += 256) dst[i] = bins[i];
    }
    #undef LA
    #undef LB
}

// ---------------------------------------------------------------------------
// K2: GEMM2  part[kc][b][d] = sum_{k in chunk kc} P'[b,k] * W[k,d]
// P' staged from s-major Pt_part, summing both split-K halves on the fly.
// Tile 64b x 64d, KT=32. Grid (D/64, NS2) = 1024 blocks = 4 waves/SIMD.
// Blocks (x<4, y==0) additionally reduce pcs -> colsum (ready pre-launch).
// ---------------------------------------------------------------------------
__global__ __launch_bounds__(256) void k_gemm2(
        const float* __restrict__ Pt_part, const float* __restrict__ W,
        float* __restrict__ part, const float* __restrict__ pcs,
        float* __restrict__ colsum, int Srows, int Dd) {
    __shared__ float lA[KT][64];    // [k][b]
    __shared__ float lB[KT][64];    // [k][d]
    int tid = threadIdx.x;
    int tx = tid & 15;   // d: 4 each
    int ty = tid >> 4;   // b: 4 each
    int d0 = blockIdx.x * 64;
    int kchunk = Srows / NS2;          // 128
    int kb = blockIdx.y * kchunk;
    size_t half = (size_t)Srows * 64;

    float4 acc[4];
    #pragma unroll
    for (int j = 0; j < 4; j++) { acc[j].x = acc[j].y = acc[j].z = acc[j].w = 0.f; }

    for (int kt = 0; kt < kchunk; kt += KT) {
        #pragma unroll
        for (int i = 0; i < 8; i++) {          // 32k x 64b
            int idx = tid + i * 256;
            int r = idx & 63, c = idx >> 6;    // r=b, c=k
            size_t src = (size_t)(kb + kt + c) * 64 + r;
            lA[c][r] = Pt_part[src] + Pt_part[half + src];
        }
        #pragma unroll
        for (int i = 0; i < 8; i++) {          // 32k x 64d
            int idx = tid + i * 256;
            int c = idx & 63, r = idx >> 6;    // c=d, r=k
            lB[r][c] = W[(size_t)(kb + kt + r) * Dd + d0 + c];
        }
        __syncthreads();
        #pragma unroll
        for (int k = 0; k < KT; k++) {
            float4 av = *(const float4*)&lA[k][ty * 4];
            float4 bv = *(const float4*)&lB[k][tx * 4];
            acc[0].x += av.x * bv.x; acc[0].y += av.x * bv.y; acc[0].z += av.x * bv.z; acc[0].w += av.x * bv.w;
            acc[1].x += av.y * bv.x; acc[1].y += av.y * bv.y; acc[1].z += av.y * bv.z; acc[1].w += av.y * bv.w;
            acc[2].x += av.z * bv.x; acc[2].y += av.z * bv.y; acc[2].z += av.z * bv.z; acc[2].w += av.z * bv.w;
            acc[3].x += av.w * bv.x; acc[3].y += av.w * bv.y; acc[3].z += av.w * bv.z; acc[3].w += av.w * bv.w;
        }
        __syncthreads();
    }
    #pragma unroll
    for (int j = 0; j < 4; j++) {
        int b = ty * 4 + j;
        *(float4*)&part[((size_t)blockIdx.y * 64 + b) * Dd + d0 + tx * 4] = acc[j];
    }

    // colsum side-job on 4 blocks (pcs complete before this kernel launched)
    if (blockIdx.y == 0 && blockIdx.x < 4) {
        int d = blockIdx.x * 256 + tid;
        float s = 0.f;
        #pragma unroll 8
        for (int c = 0; c < SCAT; c++) s += pcs[(size_t)c * Dd + d];
        colsum[d] = s;
    }
}

// ---------------------------------------------------------------------------
// K3: epilogue  out[b,d] = gscale[b] * (sum_kc part[kc][b][d] + colsum[d])
// ---------------------------------------------------------------------------
__global__ void k_epi(const float* __restrict__ part, const float* __restrict__ colsum,
                      const float* __restrict__ gscale, float* __restrict__ out,
                      int Dd, int Bdim) {
    int idx = blockIdx.x * 256 + threadIdx.x;
    if (idx >= Bdim * Dd) return;
    int b = idx / Dd;
    int d = idx - b * Dd;
    float s = 0.f;
    #pragma unroll 8
    for (int kc = 0; kc < NS2; kc++)
        s += part[((size_t)kc * Bdim + b) * Dd + d];
    out[idx] = gscale[b] * (s + colsum[d]);
}

extern "C" void kernel_launch(void* const* d_in, const int* in_sizes, int n_in,
                              void* d_out, int out_size, void* d_ws, size_t ws_size,
                              hipStream_t stream) {
    const float* H  = (const float*)d_in[0];
    const float* G  = (const float*)d_in[1];
    const float* Sg = (const float*)d_in[2];
    const float* ew = (const float*)d_in[3];
    const int*   ed = (const int*)d_in[4];
    const int*   es = (const int*)d_in[5];

    const int B = 64;
    const int F = in_sizes[0] / B;        // 512
    const int S = in_sizes[2] / F;        // 8192
    const int E = in_sizes[3];            // 500000
    const int D = out_size / B;           // 1024
    float* out = (float*)d_out;

    // workspace layout (floats); every buffer fully written before read
    float* ws = (float*)d_ws;
    size_t off = 0;
    float* rinv    = ws + off; off += (size_t)S;                 // 8192
    float* Hs      = ws + off; off += (size_t)B * F;             // 32768
    float* gscale  = ws + off; off += 256;
    float* colsum  = ws + off; off += (size_t)D;                 // 1024
    float* W       = ws + off; off += (size_t)S * D;             // 8.39M
    float* Pt_part = ws + off; off += (size_t)KC1 * S * B;       // 1.05M
    float* pcs     = ws + off; off += (size_t)SCAT * D;          // 524288
    float* part    = ws + off; off += (size_t)NS2 * B * D;       // 4.19M

    // K0: norms + W-zero (S blocks zero one W row each)
    k_norms<<<S + B, 256, 0, stream>>>(Sg, H, G, rinv, Hs, gscale, W, S, F, B, D);
    // K1: gemm1 (512 blocks) || scatter (512 blocks)
    k_g1scat<<<NG1 + SCAT, 256, 0, stream>>>(Hs, Sg, rinv, Pt_part,
                                             ew, ed, es, W, pcs,
                                             S, F, F / KC1, E, D);
    // K2: gemm2 + colsum side-job
    dim3 g2(D / 64, NS2);
    k_gemm2<<<g2, 256, 0, stream>>>(Pt_part, W, part, pcs, colsum, S, D);
    // K3: epilogue
    k_epi<<<(B * D + 255) / 256, 256, 0, stream>>>(part, colsum, gscale, out, D, B);
}